// Round 7
// baseline (147.631 us; speedup 1.0000x reference)
//
#include <hip/hip_runtime.h>
#include <hip/hip_bf16.h>

// AdditiveAttention: B=8, Q=128, V=512, H=512.
// out = [context (B*Q*H) | weights (B*Q*V)] fp32.
// ws: qp [1024*512] f32 @0, vp [4096*512] f32 @2MB (10MB).
// bc dropped (softmax shift-invariant); sum_h wc[h] const also cancels.
// Score math: tanh(y)=1-2r, r=1/(2^(C*y)+1), C=2*log2(e);
//   softmax arg = -C * sum_h wc[h]*r  (consts dropped).
// HARD RULE (R0..R5): NO min-occupancy arg in launch_bounds, ever.
//   Plain bounds = zero scratch; hinted = 9.6/118/576MB spill traffic.
// R8 budget (R6 counters): fill(harness L3 poison) 44us fixed + proj ~44 +
//   score 42.8 + finish ~12. Score occupancy lever exhausted (VALUBusy 55%).
// R9: proj re-tiled 64x64 -> 64x32, grid (8,80)->(16,80) = 1280 blocks =
//   exactly 5.0 blocks/CU (was 2.5, imbalanced). proj is ~9x above its
//   ~5us issue floor => latency/barrier-bound at 2.5 waves/SIMD; doubling
//   resident waves + perfect balance attacks that. LDS 27.6KB/block.

#define C_SCALE 2.8853900817779268f

typedef __attribute__((ext_vector_type(8))) short short8;
typedef __attribute__((ext_vector_type(4))) float f32x4;

__device__ __forceinline__ float fexp2(float x) { return __builtin_amdgcn_exp2f(x); }
__device__ __forceinline__ float frcp(float x)  { return __builtin_amdgcn_rcpf(x); }

// fp32->bf16 split: hi = RNE(x); lo = trunc_bf16(x - hi).
__device__ __forceinline__ void bf_split(float x, short& hi, short& lo) {
  unsigned u = __builtin_bit_cast(unsigned, x);
  unsigned r = u + 0x7fffu + ((u >> 16) & 1u);
  hi = (short)(r >> 16);
  float hf = __builtin_bit_cast(float, r & 0xffff0000u);
  lo = (short)(__builtin_bit_cast(unsigned, x - hf) >> 16);
}

// ---------------- split-bf16 MFMA GEMM ---------------------------------------
// out[m][n] = sum_k A[m][k]*W[n][k] + bias[n].  N=K=512.
// x = hi + lo (both bf16); D = Ahi*Whi + Ahi*Wlo + Alo*Whi (lo*lo dropped).
// Tile 64(M) x 32(N), KC=64. by<16 -> query rows (qp), else values rows (vp).
// Grid (16,80) = 1280 blocks = 5 blocks/CU exact. LDS rows padded to 72
// shorts (144B): stride-72 row reads = 2-way bank alias (free).
__global__ __launch_bounds__(256) void proj_gemm_mfma(
    const float* __restrict__ query, const float* __restrict__ values,
    const float* __restrict__ Wq, const float* __restrict__ Wv,
    const float* __restrict__ bq, const float* __restrict__ bv,
    float* __restrict__ qp, float* __restrict__ vp)
{
  __shared__ short sAhi[64 * 72];
  __shared__ short sAlo[64 * 72];
  __shared__ short sWhi[32 * 72];
  __shared__ short sWlo[32 * 72];

  const int t    = threadIdx.x;
  const int lane = t & 63;
  const int w    = t >> 6;                  // wave 0..3
  const int by   = blockIdx.y;
  const bool isQ = (by < 16);
  const float* A    = isQ ? query : values;
  const float* W    = isQ ? Wq : Wv;
  const float* bias = isQ ? bq : bv;
  float*       out  = isQ ? qp : vp;
  const int m0 = (isQ ? by : (by - 16)) << 6;
  const int n0 = blockIdx.x << 5;           // 32-wide N tile

  // A staging: thread t, iter p(0..3): row = t>>2 (64 rows), f4-col = p*4+(t&3)
  // W staging: thread t, iter p(0..1): row = t>>3 (32 rows), f4-col = p*8+(t&7)
  const float* Ap = A + (size_t)(m0 + (t >> 2)) * 512 + ((t & 3) << 2);
  const float* Wp = W + (size_t)(n0 + (t >> 3)) * 512 + ((t & 7) << 2);

  const int mw = (w & 1) << 5, nw = (w >> 1) << 4;   // wave's 32x16 quadrant
  const int frow = lane & 15, fquad = lane >> 4;

  f32x4 acc[2] = {};                        // mt = 0,1 ; single nt
  float4 pfA[4], pfW[2];
#pragma unroll
  for (int p = 0; p < 4; ++p) pfA[p] = *(const float4*)(Ap + (p << 4));
#pragma unroll
  for (int p = 0; p < 2; ++p) pfW[p] = *(const float4*)(Wp + (p << 5));

  for (int kc = 0; kc < 512; kc += 64) {
    __syncthreads();
#pragma unroll
    for (int p = 0; p < 4; ++p) {
      float av[4] = {pfA[p].x, pfA[p].y, pfA[p].z, pfA[p].w};
      short4 ah, al;
      short* ahp = (short*)&ah; short* alp = (short*)&al;
#pragma unroll
      for (int k = 0; k < 4; ++k) bf_split(av[k], ahp[k], alp[k]);
      const int ofs = (t >> 2) * 72 + ((p << 2) + (t & 3)) * 4;
      *(short4*)&sAhi[ofs] = ah; *(short4*)&sAlo[ofs] = al;
    }
#pragma unroll
    for (int p = 0; p < 2; ++p) {
      float wv[4] = {pfW[p].x, pfW[p].y, pfW[p].z, pfW[p].w};
      short4 wh, wl;
      short* whp = (short*)&wh; short* wlp = (short*)&wl;
#pragma unroll
      for (int k = 0; k < 4; ++k) bf_split(wv[k], whp[k], wlp[k]);
      const int ofs = (t >> 3) * 72 + ((p << 3) + (t & 7)) * 4;
      *(short4*)&sWhi[ofs] = wh; *(short4*)&sWlo[ofs] = wl;
    }
    __syncthreads();
    if (kc + 64 < 512) {
#pragma unroll
      for (int p = 0; p < 4; ++p)
        pfA[p] = *(const float4*)(Ap + kc + 64 + (p << 4));
#pragma unroll
      for (int p = 0; p < 2; ++p)
        pfW[p] = *(const float4*)(Wp + kc + 64 + (p << 5));
    }
#pragma unroll
    for (int kb = 0; kb < 2; ++kb) {
      const int ko = kb * 32 + fquad * 8;
      short8 ahi[2], alo[2], whi, wlo;
#pragma unroll
      for (int mt = 0; mt < 2; ++mt) {
        const int r = (mw + mt * 16 + frow) * 72 + ko;
        ahi[mt] = *(const short8*)&sAhi[r];
        alo[mt] = *(const short8*)&sAlo[r];
      }
      {
        const int r = (nw + frow) * 72 + ko;
        whi = *(const short8*)&sWhi[r];
        wlo = *(const short8*)&sWlo[r];
      }
#pragma unroll
      for (int mt = 0; mt < 2; ++mt) {
        acc[mt] = __builtin_amdgcn_mfma_f32_16x16x32_bf16(
            alo[mt], whi, acc[mt], 0, 0, 0);
        acc[mt] = __builtin_amdgcn_mfma_f32_16x16x32_bf16(
            ahi[mt], wlo, acc[mt], 0, 0, 0);
        acc[mt] = __builtin_amdgcn_mfma_f32_16x16x32_bf16(
            ahi[mt], whi, acc[mt], 0, 0, 0);
      }
    }
  }

  // epilogue: C/D layout col = lane&15, row = (lane>>4)*4 + reg
  {
    const int n = n0 + nw + frow;
    const float bn = bias[n];
#pragma unroll
    for (int mt = 0; mt < 2; ++mt) {
      float vreg[4] = {acc[mt].x, acc[mt].y, acc[mt].z, acc[mt].w};
#pragma unroll
      for (int r = 0; r < 4; ++r) {
        const int m = m0 + mw + mt * 16 + fquad * 4 + r;
        out[(size_t)m * 512 + n] = vreg[r] + bn;
      }
    }
  }
}

// ---------------- score chunk (NU slot-steps, 16 slots apart) ----------------
template<int NU>
__device__ __forceinline__ void score_chunkA(
    const float* __restrict__ vpb, const float* __restrict__ qr0,
    const float* __restrict__ wc, const int* idxs, float* __restrict__ ow0,
    int s00, int i0, int hi, int c4, int lane)
{
  int su[NU];
  unsigned voff[NU];
  float a0[NU], a1[NU];
#pragma unroll
  for (int u = 0; u < NU; ++u) {
    su[u] = s00 + ((i0 + u) << 4);
    voff[u] = ((unsigned)idxs[su[u] & 511] << 9) + (unsigned)c4;
    a0[u] = 0.f; a1[u] = 0.f;
  }
#pragma unroll
  for (int j = 0; j < 8; ++j) {
    const int hoff = (j << 6) + c4;
    float4 vv[NU];
#pragma unroll
    for (int u = 0; u < NU; ++u)
      vv[u] = *(const float4*)(vpb + voff[u] + (unsigned)(j << 6));
    const float4 q0v = *(const float4*)(qr0 + hoff);
    const float4 q1v = *(const float4*)(qr0 + 512 + hoff);
    const float4 wcv = *(const float4*)(wc + hoff);
    const float cq0[4] = {C_SCALE * q0v.x, C_SCALE * q0v.y,
                          C_SCALE * q0v.z, C_SCALE * q0v.w};
    const float dd[4]  = {fexp2(C_SCALE * (q1v.x - q0v.x)),
                          fexp2(C_SCALE * (q1v.y - q0v.y)),
                          fexp2(C_SCALE * (q1v.z - q0v.z)),
                          fexp2(C_SCALE * (q1v.w - q0v.w))};
    const float wc4[4] = {wcv.x, wcv.y, wcv.z, wcv.w};
#pragma unroll
    for (int u = 0; u < NU; ++u) {
      const float vq[4] = {vv[u].x, vv[u].y, vv[u].z, vv[u].w};
#pragma unroll
      for (int k = 0; k < 4; ++k) {
        float x0 = __builtin_fmaf(C_SCALE, vq[k], cq0[k]);
        float e0 = fexp2(x0);
        float e1 = e0 * dd[k];
        float d0 = e0 + 1.0f;
        float d1 = e1 + 1.0f;
        float P  = frcp(d0 * d1);          // pair-rcp: r0=d1*P, r1=d0*P
        a0[u] = __builtin_fmaf(wc4[k] * d1, P, a0[u]);
        a1[u] = __builtin_fmaf(wc4[k] * d0, P, a1[u]);
      }
    }
  }
#pragma unroll
  for (int u = 0; u < NU; ++u) {
    float s0 = a0[u], s1 = a1[u];
#pragma unroll
    for (int off = 1; off < 16; off <<= 1) {
      s0 += __shfl_xor(s0, off, 64);
      s1 += __shfl_xor(s1, off, 64);
    }
    if (su[u] < hi && (lane & 15) == (i0 + u)) {   // i0+u <= 7 < 16
      ow0[su[u]]       = s0;
      ow0[512 + su[u]] = s1;
    }
  }
}

// ---------------- attn kernel A: raw scores ----------------------------------
// Grid (512 qpairs, 4 slot-chunks) x 256 thr (4 waves).
// PLAIN launch_bounds (no min-occupancy arg -- see HARD RULE above).
// Block covers slots [cnt*c/4, cnt*(c+1)/4); wave w, iter i owns slots
// lo + i*16 + w*4 + g (g = lane>>4); 16 h-lanes per slot (c4 = (lane&15)*4).
// Raw scores written slot-ordered into out_w rows (staging; finish rewrites).
__global__ __launch_bounds__(256) void attn_score(
    const float* __restrict__ qp, const float* __restrict__ vp,
    const int* __restrict__ mask, const float* __restrict__ wc,
    float* __restrict__ out_w)
{
  __shared__ int idxs[512];
  __shared__ int cnt8[8];

  const int t    = threadIdx.x;
  const int lane = t & 63;
  const int w    = t >> 6;                 // 0..3
  const int b    = blockIdx.x & 7;
  const int qg   = blockIdx.x >> 3;
  const int rowbase = b * 128 + qg * 2;

  idxs[t] = 0; idxs[t + 256] = 0;
  const int mv0 = mask[b * 512 + t];
  const int mv1 = mask[b * 512 + 256 + t];
  const unsigned long long bal0 = __ballot(mv0 != 0);
  const unsigned long long bal1 = __ballot(mv1 != 0);
  if (lane == 0) { cnt8[w] = __popcll(bal0); cnt8[w + 4] = __popcll(bal1); }
  __syncthreads();
  int cnt = 0, off0 = 0, off4 = 0;
#pragma unroll
  for (int j = 0; j < 8; ++j) {
    if (j == w)     off0 = cnt;
    if (j == w + 4) off4 = cnt;
    cnt += cnt8[j];
  }
  if (mv0) idxs[off0 + __popcll(bal0 & ((1ull << lane) - 1ull))] = t;
  if (mv1) idxs[off4 + __popcll(bal1 & ((1ull << lane) - 1ull))] = t + 256;
  __syncthreads();

  const int c  = blockIdx.y;               // slot-chunk 0..3
  const int lo = (cnt * c) >> 2;
  const int hi = (cnt * (c + 1)) >> 2;
  const int NI = (hi - lo + 15) >> 4;      // 16-slot steps (<=8)
  const int g  = lane >> 4;
  const int c4 = (lane & 15) << 2;
  const int s00 = lo + (w << 2) + g;

  const float* vpb = vp + (size_t)b * 512 * 512;
  const float* qr0 = qp + (size_t)rowbase * 512;
  float* ow0 = out_w + (size_t)rowbase * 512;

  int i0 = 0;
  for (; i0 + 2 <= NI; i0 += 2)
    score_chunkA<2>(vpb, qr0, wc, idxs, ow0, s00, i0, hi, c4, lane);
  for (; i0 < NI; ++i0)
    score_chunkA<1>(vpb, qr0, wc, idxs, ow0, s00, i0, hi, c4, lane);
}

// ---------------- attn kernel B: softmax + weights + context -----------------
// 512 blocks x 512 thr (8 waves). Reads slot-ordered raw scores from out_w,
// softmax (min-shift, invalid slots masked to +BIG), rewrites out_w rows
// coalesced via inverse map, context with wave-per-h-window.
__global__ __launch_bounds__(512) void attn_finish(
    const float* __restrict__ values, const int* __restrict__ mask,
    float* __restrict__ out_ctx, float* __restrict__ out_w)
{
  __shared__ int   idxs[512];
  __shared__ float wls2[512][2];    // final weights per slot, (q0,q1) pairs
  __shared__ int   cnt8[8];

  const int t    = threadIdx.x;
  const int lane = t & 63;
  const int w    = t >> 6;                 // 0..7
  const int b    = blockIdx.x & 7;
  const int qg   = blockIdx.x >> 3;
  const int rowbase = b * 128 + qg * 2;

  ((float*)wls2)[t]       = 0.f;
  ((float*)wls2)[t + 512] = 0.f;
  idxs[t] = 0;
  const int mv = mask[b * 512 + t];
  const unsigned long long bal = __ballot(mv != 0);
  if (lane == 0) cnt8[w] = __popcll(bal);
  __syncthreads();
  int cnt = 0, offw = 0;
#pragma unroll
  for (int j = 0; j < 8; ++j) { if (j == w) offw = cnt; cnt += cnt8[j]; }
  int iinv = -1;
  if (mv) {
    iinv = offw + __popcll(bal & ((1ull << lane) - 1ull));
    idxs[iinv] = t;
  }
  __syncthreads();

  // ---- softmax: waves 0-3 -> q0, 4-7 -> q1 (dup compute; waves 0/4 write)
  {
    const int mq = (w >= 4) ? 1 : 0;
    const float* srow = out_w + (size_t)(rowbase + mq) * 512;
    float4 u0 = ((const float4*)srow)[lane * 2];
    float4 u1 = ((const float4*)srow)[lane * 2 + 1];
    float s8[8] = {u0.x, u0.y, u0.z, u0.w, u1.x, u1.y, u1.z, u1.w};
#pragma unroll
    for (int k = 0; k < 8; ++k)
      if (lane * 8 + k >= cnt) s8[k] = 3.4e38f;           // mask garbage slots
    float m = s8[0];
#pragma unroll
    for (int k = 1; k < 8; ++k) m = fminf(m, s8[k]);      // min: weight=exp2(C*(m-s))
#pragma unroll
    for (int off = 1; off < 64; off <<= 1) m = fminf(m, __shfl_xor(m, off, 64));
    float e[8], S = 0.f;
#pragma unroll
    for (int k = 0; k < 8; ++k) { e[k] = fexp2(C_SCALE * (m - s8[k])); S += e[k]; }
#pragma unroll
    for (int off = 1; off < 64; off <<= 1) S += __shfl_xor(S, off, 64);
    const float rinv = frcp(S);
    if (w == 0 || w == 4) {
#pragma unroll
      for (int k = 0; k < 8; ++k) {
        const int s = lane * 8 + k;
        if (s < cnt) wls2[s][mq] = e[k] * rinv;
      }
    }
  }
  __syncthreads();

  // ---- final weight rows (coalesced; zeros where masked out)
  {
    float w0 = 0.f, w1 = 0.f;
    if (iinv >= 0) { w0 = wls2[iinv][0]; w1 = wls2[iinv][1]; }
    out_w[(size_t)rowbase * 512 + t]       = w0;
    out_w[(size_t)(rowbase + 1) * 512 + t] = w1;
  }

  // ---- context: wave w owns h-window [w*64, w*64+64)
  const int NC = (cnt + 3) >> 2;
  const int g  = lane >> 4;
  const int c4 = (lane & 15) << 2;
  const unsigned hbase = (unsigned)(w * 64 + c4);
  const float* vb = values + (size_t)b * 512 * 512;
  float c0[4] = {0.f, 0.f, 0.f, 0.f}, c1[4] = {0.f, 0.f, 0.f, 0.f};
#pragma unroll 4
  for (int i = 0; i < NC; ++i) {
    const int s = (i << 2) + g;
    const unsigned ro = ((unsigned)idxs[s] << 9) + hbase;
    const float2 wg = *(const float2*)&wls2[s][0];        // padded slots: 0
    const float4 v4 = *(const float4*)(vb + ro);
    float vv[4] = {v4.x, v4.y, v4.z, v4.w};
#pragma unroll
    for (int k = 0; k < 4; ++k) {
      c0[k] = __builtin_fmaf(wg.x, vv[k], c0[k]);
      c1[k] = __builtin_fmaf(wg.y, vv[k], c1[k]);
    }
  }
#pragma unroll
  for (int k = 0; k < 4; ++k) {                           // reduce over g
    c0[k] += __shfl_xor(c0[k], 16, 64); c0[k] += __shfl_xor(c0[k], 32, 64);
    c1[k] += __shfl_xor(c1[k], 16, 64); c1[k] += __shfl_xor(c1[k], 32, 64);
  }
  if (lane < 16) {
    float4 o0 = {c0[0], c0[1], c0[2], c0[3]};
    float4 o1 = {c1[0], c1[1], c1[2], c1[3]};
    *(float4*)(out_ctx + (size_t)rowbase * 512 + w * 64 + lane * 4)       = o0;
    *(float4*)(out_ctx + (size_t)(rowbase + 1) * 512 + w * 64 + lane * 4) = o1;
  }
}

extern "C" void kernel_launch(void* const* d_in, const int* in_sizes, int n_in,
                              void* d_out, int out_size, void* d_ws, size_t ws_size,
                              hipStream_t stream) {
  const float* query  = (const float*)d_in[0];
  const float* values = (const float*)d_in[1];
  const int*   mask   = (const int*)d_in[2];
  const float* Wq     = (const float*)d_in[3];
  const float* bq     = (const float*)d_in[4];
  const float* Wv     = (const float*)d_in[5];
  const float* bv     = (const float*)d_in[6];
  const float* wc     = (const float*)d_in[7];
  // d_in[8] = bc: no effect on outputs (softmax shift-invariance) -> dropped.

  float* out   = (float*)d_out;
  float* out_w = out + (size_t)8 * 128 * 512;
  float* qp    = (float*)d_ws;                 // 1024 x 512
  float* vp    = qp + (size_t)1024 * 512;      // 4096 x 512

  proj_gemm_mfma<<<dim3(16, 80), 256, 0, stream>>>(query, values, Wq, Wv, bq, bv, qp, vp);
  attn_score<<<dim3(512, 4), 256, 0, stream>>>(qp, vp, mask, wc, out_w);
  attn_finish<<<512, 512, 0, stream>>>(values, mask, out, out_w);
}

// Round 8
// 147.257 us; speedup vs baseline: 1.0025x; 1.0025x over previous
//
#include <hip/hip_runtime.h>
#include <hip/hip_bf16.h>

// AdditiveAttention: B=8, Q=128, V=512, H=512.
// out = [context (B*Q*H) | weights (B*Q*V)] fp32.
// ws: qp [1024*512] f32 @0, vp [4096*512] f32 @2MB (10MB).
// bc dropped (softmax shift-invariant); sum_h wc[h] const also cancels.
// Score math: tanh(y)=1-2r, r=1/(2^(C*y)+1), C=2*log2(e);
//   softmax arg = -C * sum_h wc[h]*r  (consts dropped).
// HARD RULE (R0..R5): NO min-occupancy arg in launch_bounds, ever.
//   Plain bounds = zero scratch; hinted = 9.6/118/576MB spill traffic.
// R9 (proj 64x32 retile): neutral -> REVERTED to R6 64x64, grid (8,80).
// R10: score j-loop was paying a serial q-load(L1~100cy)+dd-exp2(32cy)
//   chain per j against only 256cy of compute (VALUBusy 56% == predicted
//   66%). Hoist cq0/dd/wc for all 8 j's into 96 statically-indexed regs
//   ONCE per block; chunks widened to NU=4 (4-deep vv load pipelining).
//   j-body now = 4 loads + 16 pair-computes, no dependent scalar chain.

#define C_SCALE 2.8853900817779268f

typedef __attribute__((ext_vector_type(8))) short short8;
typedef __attribute__((ext_vector_type(4))) float f32x4;

__device__ __forceinline__ float fexp2(float x) { return __builtin_amdgcn_exp2f(x); }
__device__ __forceinline__ float frcp(float x)  { return __builtin_amdgcn_rcpf(x); }

// fp32->bf16 split: hi = RNE(x); lo = trunc_bf16(x - hi).
__device__ __forceinline__ void bf_split(float x, short& hi, short& lo) {
  unsigned u = __builtin_bit_cast(unsigned, x);
  unsigned r = u + 0x7fffu + ((u >> 16) & 1u);
  hi = (short)(r >> 16);
  float hf = __builtin_bit_cast(float, r & 0xffff0000u);
  lo = (short)(__builtin_bit_cast(unsigned, x - hf) >> 16);
}

// ---------------- split-bf16 MFMA GEMM ---------------------------------------
// out[m][n] = sum_k A[m][k]*W[n][k] + bias[n].  N=K=512.
// x = hi + lo (both bf16); D = Ahi*Whi + Ahi*Wlo + Alo*Whi (lo*lo dropped).
// 64x64 tile, KC=64. by<16 -> query rows (qp), else values rows (vp).
// LDS rows padded to 72 shorts (144B). Grid (8,80).
__global__ __launch_bounds__(256) void proj_gemm_mfma(
    const float* __restrict__ query, const float* __restrict__ values,
    const float* __restrict__ Wq, const float* __restrict__ Wv,
    const float* __restrict__ bq, const float* __restrict__ bv,
    float* __restrict__ qp, float* __restrict__ vp)
{
  __shared__ short sAhi[64 * 72];
  __shared__ short sAlo[64 * 72];
  __shared__ short sWhi[64 * 72];
  __shared__ short sWlo[64 * 72];

  const int t    = threadIdx.x;
  const int lane = t & 63;
  const int w    = t >> 6;                  // wave 0..3
  const int by   = blockIdx.y;
  const bool isQ = (by < 16);
  const float* A    = isQ ? query : values;
  const float* W    = isQ ? Wq : Wv;
  const float* bias = isQ ? bq : bv;
  float*       out  = isQ ? qp : vp;
  const int m0 = (isQ ? by : (by - 16)) << 6;
  const int n0 = blockIdx.x << 6;

  // staging map: thread t, iter p: row = t>>2 (64 rows), f4-col = p*4 + (t&3)
  const int srow = t >> 2, scol = t & 3;
  const float* Ap = A + (size_t)(m0 + srow) * 512 + (scol << 2);
  const float* Wp = W + (size_t)(n0 + srow) * 512 + (scol << 2);

  const int mw = (w & 1) << 5, nw = (w >> 1) << 5;   // wave's 32x32 quadrant
  const int frow = lane & 15, fquad = lane >> 4;

  f32x4 acc[2][2] = {};
  float4 pfA[4], pfW[4];
#pragma unroll
  for (int p = 0; p < 4; ++p) {
    pfA[p] = *(const float4*)(Ap + (p << 4));
    pfW[p] = *(const float4*)(Wp + (p << 4));
  }

  for (int kc = 0; kc < 512; kc += 64) {
    __syncthreads();
#pragma unroll
    for (int p = 0; p < 4; ++p) {
      float av[4] = {pfA[p].x, pfA[p].y, pfA[p].z, pfA[p].w};
      float wv[4] = {pfW[p].x, pfW[p].y, pfW[p].z, pfW[p].w};
      short4 ah, al, wh, wl;
      short* ahp = (short*)&ah; short* alp = (short*)&al;
      short* whp = (short*)&wh; short* wlp = (short*)&wl;
#pragma unroll
      for (int k = 0; k < 4; ++k) {
        bf_split(av[k], ahp[k], alp[k]);
        bf_split(wv[k], whp[k], wlp[k]);
      }
      const int ofs = srow * 72 + ((p << 2) + scol) * 4;
      *(short4*)&sAhi[ofs] = ah; *(short4*)&sAlo[ofs] = al;
      *(short4*)&sWhi[ofs] = wh; *(short4*)&sWlo[ofs] = wl;
    }
    __syncthreads();
    if (kc + 64 < 512) {
#pragma unroll
      for (int p = 0; p < 4; ++p) {
        pfA[p] = *(const float4*)(Ap + kc + 64 + (p << 4));
        pfW[p] = *(const float4*)(Wp + kc + 64 + (p << 4));
      }
    }
#pragma unroll
    for (int kb = 0; kb < 2; ++kb) {
      const int ko = kb * 32 + fquad * 8;
      short8 ahi[2], alo[2], whi[2], wlo[2];
#pragma unroll
      for (int mt = 0; mt < 2; ++mt) {
        const int r = (mw + mt * 16 + frow) * 72 + ko;
        ahi[mt] = *(const short8*)&sAhi[r];
        alo[mt] = *(const short8*)&sAlo[r];
      }
#pragma unroll
      for (int nt = 0; nt < 2; ++nt) {
        const int r = (nw + nt * 16 + frow) * 72 + ko;
        whi[nt] = *(const short8*)&sWhi[r];
        wlo[nt] = *(const short8*)&sWlo[r];
      }
#pragma unroll
      for (int mt = 0; mt < 2; ++mt)
#pragma unroll
        for (int nt = 0; nt < 2; ++nt) {
          acc[mt][nt] = __builtin_amdgcn_mfma_f32_16x16x32_bf16(
              alo[mt], whi[nt], acc[mt][nt], 0, 0, 0);
          acc[mt][nt] = __builtin_amdgcn_mfma_f32_16x16x32_bf16(
              ahi[mt], wlo[nt], acc[mt][nt], 0, 0, 0);
          acc[mt][nt] = __builtin_amdgcn_mfma_f32_16x16x32_bf16(
              ahi[mt], whi[nt], acc[mt][nt], 0, 0, 0);
        }
    }
  }

  // epilogue: C/D layout col = lane&15, row = (lane>>4)*4 + reg
#pragma unroll
  for (int nt = 0; nt < 2; ++nt) {
    const int n = n0 + nw + nt * 16 + frow;
    const float bn = bias[n];
#pragma unroll
    for (int mt = 0; mt < 2; ++mt) {
      float vreg[4] = {acc[mt][nt].x, acc[mt][nt].y, acc[mt][nt].z, acc[mt][nt].w};
#pragma unroll
      for (int r = 0; r < 4; ++r) {
        const int m = m0 + mw + mt * 16 + fquad * 4 + r;
        out[(size_t)m * 512 + n] = vreg[r] + bn;
      }
    }
  }
}

// ---------------- score chunk (NU slot-steps, 16 slots apart) ----------------
// q-state (cq0/dd/wc for all 8 j) hoisted by caller into registers; j-body
// here is pure: NU vv loads + NU*4 pair-computes. Static indexing only.
template<int NU>
__device__ __forceinline__ void score_chunkB(
    const float* __restrict__ vpb,
    const float (&cq0a)[8][4], const float (&dda)[8][4], const float (&wca)[8][4],
    const int* idxs, float* __restrict__ ow0,
    int s00, int i0, int hi, int c4, int lane)
{
  int su[NU];
  unsigned voff[NU];
  float a0[NU], a1[NU];
#pragma unroll
  for (int u = 0; u < NU; ++u) {
    su[u] = s00 + ((i0 + u) << 4);
    voff[u] = ((unsigned)idxs[su[u] & 511] << 9) + (unsigned)c4;
    a0[u] = 0.f; a1[u] = 0.f;
  }
#pragma unroll
  for (int j = 0; j < 8; ++j) {
    float4 vv[NU];
#pragma unroll
    for (int u = 0; u < NU; ++u)
      vv[u] = *(const float4*)(vpb + voff[u] + (unsigned)(j << 6));
#pragma unroll
    for (int u = 0; u < NU; ++u) {
      const float vq[4] = {vv[u].x, vv[u].y, vv[u].z, vv[u].w};
#pragma unroll
      for (int k = 0; k < 4; ++k) {
        float x0 = __builtin_fmaf(C_SCALE, vq[k], cq0a[j][k]);
        float e0 = fexp2(x0);
        float e1 = e0 * dda[j][k];
        float d0 = e0 + 1.0f;
        float d1 = e1 + 1.0f;
        float P  = frcp(d0 * d1);          // pair-rcp: r0=d1*P, r1=d0*P
        a0[u] = __builtin_fmaf(wca[j][k] * d1, P, a0[u]);
        a1[u] = __builtin_fmaf(wca[j][k] * d0, P, a1[u]);
      }
    }
  }
#pragma unroll
  for (int u = 0; u < NU; ++u) {
    float s0 = a0[u], s1 = a1[u];
#pragma unroll
    for (int off = 1; off < 16; off <<= 1) {
      s0 += __shfl_xor(s0, off, 64);
      s1 += __shfl_xor(s1, off, 64);
    }
    if (su[u] < hi && (lane & 15) == (i0 + u)) {   // i0+u <= 7 < 16
      ow0[su[u]]       = s0;
      ow0[512 + su[u]] = s1;
    }
  }
}

// ---------------- attn kernel A: raw scores ----------------------------------
// Grid (512 qpairs, 4 slot-chunks) x 256 thr (4 waves).
// PLAIN launch_bounds (no min-occupancy arg -- see HARD RULE above).
// Block covers slots [cnt*c/4, cnt*(c+1)/4); wave w, iter i owns slots
// lo + i*16 + w*4 + g (g = lane>>4); 16 h-lanes per slot (c4 = (lane&15)*4).
// Raw scores written slot-ordered into out_w rows (staging; finish rewrites).
__global__ __launch_bounds__(256) void attn_score(
    const float* __restrict__ qp, const float* __restrict__ vp,
    const int* __restrict__ mask, const float* __restrict__ wc,
    float* __restrict__ out_w)
{
  __shared__ int idxs[512];
  __shared__ int cnt8[8];

  const int t    = threadIdx.x;
  const int lane = t & 63;
  const int w    = t >> 6;                 // 0..3
  const int b    = blockIdx.x & 7;
  const int qg   = blockIdx.x >> 3;
  const int rowbase = b * 128 + qg * 2;

  idxs[t] = 0; idxs[t + 256] = 0;
  const int mv0 = mask[b * 512 + t];
  const int mv1 = mask[b * 512 + 256 + t];
  const unsigned long long bal0 = __ballot(mv0 != 0);
  const unsigned long long bal1 = __ballot(mv1 != 0);
  if (lane == 0) { cnt8[w] = __popcll(bal0); cnt8[w + 4] = __popcll(bal1); }
  __syncthreads();
  int cnt = 0, off0 = 0, off4 = 0;
#pragma unroll
  for (int j = 0; j < 8; ++j) {
    if (j == w)     off0 = cnt;
    if (j == w + 4) off4 = cnt;
    cnt += cnt8[j];
  }
  if (mv0) idxs[off0 + __popcll(bal0 & ((1ull << lane) - 1ull))] = t;
  if (mv1) idxs[off4 + __popcll(bal1 & ((1ull << lane) - 1ull))] = t + 256;
  __syncthreads();

  const int c  = blockIdx.y;               // slot-chunk 0..3
  const int lo = (cnt * c) >> 2;
  const int hi = (cnt * (c + 1)) >> 2;
  const int NI = (hi - lo + 15) >> 4;      // 16-slot steps (<=8)
  const int g  = lane >> 4;
  const int c4 = (lane & 15) << 2;
  const int s00 = lo + (w << 2) + g;

  const float* vpb = vp + (size_t)b * 512 * 512;
  const float* qr0 = qp + (size_t)rowbase * 512;
  float* ow0 = out_w + (size_t)rowbase * 512;

  // ---- hoist per-block q-state for all 8 j's (96 regs, static indices)
  float cq0a[8][4], dda[8][4], wca[8][4];
#pragma unroll
  for (int j = 0; j < 8; ++j) {
    const int hoff = (j << 6) + c4;
    const float4 q0v = *(const float4*)(qr0 + hoff);
    const float4 q1v = *(const float4*)(qr0 + 512 + hoff);
    const float4 wcv = *(const float4*)(wc + hoff);
    cq0a[j][0] = C_SCALE * q0v.x; cq0a[j][1] = C_SCALE * q0v.y;
    cq0a[j][2] = C_SCALE * q0v.z; cq0a[j][3] = C_SCALE * q0v.w;
    dda[j][0] = fexp2(C_SCALE * (q1v.x - q0v.x));
    dda[j][1] = fexp2(C_SCALE * (q1v.y - q0v.y));
    dda[j][2] = fexp2(C_SCALE * (q1v.z - q0v.z));
    dda[j][3] = fexp2(C_SCALE * (q1v.w - q0v.w));
    wca[j][0] = wcv.x; wca[j][1] = wcv.y; wca[j][2] = wcv.z; wca[j][3] = wcv.w;
  }

  int i0 = 0;
  for (; i0 + 4 <= NI; i0 += 4)
    score_chunkB<4>(vpb, cq0a, dda, wca, idxs, ow0, s00, i0, hi, c4, lane);
  for (; i0 < NI; ++i0)
    score_chunkB<1>(vpb, cq0a, dda, wca, idxs, ow0, s00, i0, hi, c4, lane);
}

// ---------------- attn kernel B: softmax + weights + context -----------------
// 512 blocks x 512 thr (8 waves). Reads slot-ordered raw scores from out_w,
// softmax (min-shift, invalid slots masked to +BIG), rewrites out_w rows
// coalesced via inverse map, context with wave-per-h-window.
__global__ __launch_bounds__(512) void attn_finish(
    const float* __restrict__ values, const int* __restrict__ mask,
    float* __restrict__ out_ctx, float* __restrict__ out_w)
{
  __shared__ int   idxs[512];
  __shared__ float wls2[512][2];    // final weights per slot, (q0,q1) pairs
  __shared__ int   cnt8[8];

  const int t    = threadIdx.x;
  const int lane = t & 63;
  const int w    = t >> 6;                 // 0..7
  const int b    = blockIdx.x & 7;
  const int qg   = blockIdx.x >> 3;
  const int rowbase = b * 128 + qg * 2;

  ((float*)wls2)[t]       = 0.f;
  ((float*)wls2)[t + 512] = 0.f;
  idxs[t] = 0;
  const int mv = mask[b * 512 + t];
  const unsigned long long bal = __ballot(mv != 0);
  if (lane == 0) cnt8[w] = __popcll(bal);
  __syncthreads();
  int cnt = 0, offw = 0;
#pragma unroll
  for (int j = 0; j < 8; ++j) { if (j == w) offw = cnt; cnt += cnt8[j]; }
  int iinv = -1;
  if (mv) {
    iinv = offw + __popcll(bal & ((1ull << lane) - 1ull));
    idxs[iinv] = t;
  }
  __syncthreads();

  // ---- softmax: waves 0-3 -> q0, 4-7 -> q1 (dup compute; waves 0/4 write)
  {
    const int mq = (w >= 4) ? 1 : 0;
    const float* srow = out_w + (size_t)(rowbase + mq) * 512;
    float4 u0 = ((const float4*)srow)[lane * 2];
    float4 u1 = ((const float4*)srow)[lane * 2 + 1];
    float s8[8] = {u0.x, u0.y, u0.z, u0.w, u1.x, u1.y, u1.z, u1.w};
#pragma unroll
    for (int k = 0; k < 8; ++k)
      if (lane * 8 + k >= cnt) s8[k] = 3.4e38f;           // mask garbage slots
    float m = s8[0];
#pragma unroll
    for (int k = 1; k < 8; ++k) m = fminf(m, s8[k]);      // min: weight=exp2(C*(m-s))
#pragma unroll
    for (int off = 1; off < 64; off <<= 1) m = fminf(m, __shfl_xor(m, off, 64));
    float e[8], S = 0.f;
#pragma unroll
    for (int k = 0; k < 8; ++k) { e[k] = fexp2(C_SCALE * (m - s8[k])); S += e[k]; }
#pragma unroll
    for (int off = 1; off < 64; off <<= 1) S += __shfl_xor(S, off, 64);
    const float rinv = frcp(S);
    if (w == 0 || w == 4) {
#pragma unroll
      for (int k = 0; k < 8; ++k) {
        const int s = lane * 8 + k;
        if (s < cnt) wls2[s][mq] = e[k] * rinv;
      }
    }
  }
  __syncthreads();

  // ---- final weight rows (coalesced; zeros where masked out)
  {
    float w0 = 0.f, w1 = 0.f;
    if (iinv >= 0) { w0 = wls2[iinv][0]; w1 = wls2[iinv][1]; }
    out_w[(size_t)rowbase * 512 + t]       = w0;
    out_w[(size_t)(rowbase + 1) * 512 + t] = w1;
  }

  // ---- context: wave w owns h-window [w*64, w*64+64)
  const int NC = (cnt + 3) >> 2;
  const int g  = lane >> 4;
  const int c4 = (lane & 15) << 2;
  const unsigned hbase = (unsigned)(w * 64 + c4);
  const float* vb = values + (size_t)b * 512 * 512;
  float c0[4] = {0.f, 0.f, 0.f, 0.f}, c1[4] = {0.f, 0.f, 0.f, 0.f};
#pragma unroll 4
  for (int i = 0; i < NC; ++i) {
    const int s = (i << 2) + g;
    const unsigned ro = ((unsigned)idxs[s] << 9) + hbase;
    const float2 wg = *(const float2*)&wls2[s][0];        // padded slots: 0
    const float4 v4 = *(const float4*)(vb + ro);
    float vv[4] = {v4.x, v4.y, v4.z, v4.w};
#pragma unroll
    for (int k = 0; k < 4; ++k) {
      c0[k] = __builtin_fmaf(wg.x, vv[k], c0[k]);
      c1[k] = __builtin_fmaf(wg.y, vv[k], c1[k]);
    }
  }
#pragma unroll
  for (int k = 0; k < 4; ++k) {                           // reduce over g
    c0[k] += __shfl_xor(c0[k], 16, 64); c0[k] += __shfl_xor(c0[k], 32, 64);
    c1[k] += __shfl_xor(c1[k], 16, 64); c1[k] += __shfl_xor(c1[k], 32, 64);
  }
  if (lane < 16) {
    float4 o0 = {c0[0], c0[1], c0[2], c0[3]};
    float4 o1 = {c1[0], c1[1], c1[2], c1[3]};
    *(float4*)(out_ctx + (size_t)rowbase * 512 + w * 64 + lane * 4)       = o0;
    *(float4*)(out_ctx + (size_t)(rowbase + 1) * 512 + w * 64 + lane * 4) = o1;
  }
}

extern "C" void kernel_launch(void* const* d_in, const int* in_sizes, int n_in,
                              void* d_out, int out_size, void* d_ws, size_t ws_size,
                              hipStream_t stream) {
  const float* query  = (const float*)d_in[0];
  const float* values = (const float*)d_in[1];
  const int*   mask   = (const int*)d_in[2];
  const float* Wq     = (const float*)d_in[3];
  const float* bq     = (const float*)d_in[4];
  const float* Wv     = (const float*)d_in[5];
  const float* bv     = (const float*)d_in[6];
  const float* wc     = (const float*)d_in[7];
  // d_in[8] = bc: no effect on outputs (softmax shift-invariance) -> dropped.

  float* out   = (float*)d_out;
  float* out_w = out + (size_t)8 * 128 * 512;
  float* qp    = (float*)d_ws;                 // 1024 x 512
  float* vp    = qp + (size_t)1024 * 512;      // 4096 x 512

  proj_gemm_mfma<<<dim3(8, 80), 256, 0, stream>>>(query, values, Wq, Wv, bq, bv, qp, vp);
  attn_score<<<dim3(512, 4), 256, 0, stream>>>(qp, vp, mask, wc, out_w);
  attn_finish<<<512, 512, 0, stream>>>(values, mask, out, out_w);
}

// Round 9
// 140.696 us; speedup vs baseline: 1.0493x; 1.0466x over previous
//
#include <hip/hip_runtime.h>
#include <hip/hip_bf16.h>

// AdditiveAttention: B=8, Q=128, V=512, H=512.
// out = [context (B*Q*H) | weights (B*Q*V)] fp32.
// ws: Eq [1024*512] f32 @0, Ev [4096*512] f32 @2MB (10MB total).
// bc dropped (softmax shift-invariant); sum_h wc[h] const also cancels.
// Score math: tanh(y)=1-2r, r=1/(2^(C*y)+1), C=2*log2(e);
//   softmax arg = -C * sum_h wc[h]*r  (consts dropped).
// HARD RULE (R0..R5): NO min-occupancy arg in launch_bounds, ever.
//   Plain bounds = zero scratch; hinted = 9.6/118/576MB spill traffic.
// R10 (hoist): null -- score invariant at 43us across NU=1/2/4, hoisting,
//   occupancy 15-20%. Schedule levers exhausted at source level.
// R11: FACTORIZED EXP. 2^(C(q+v)) = 2^(Cv)*2^(Cq). proj epilogue stores
//   Ev=exp2(C*vp), Eq=exp2(C*qp) (raw qp/vp consumed by nobody else).
//   Score inner: e0=Ev*Eq0, e1=Ev*Eq1, pair-rcp -> 1 trans + 9 VALU per
//   q-pair element (was 2 trans + 9 VALU). Total exp2: 67M -> 2.6M.

#define C_SCALE 2.8853900817779268f

typedef __attribute__((ext_vector_type(8))) short short8;
typedef __attribute__((ext_vector_type(4))) float f32x4;

__device__ __forceinline__ float fexp2(float x) { return __builtin_amdgcn_exp2f(x); }
__device__ __forceinline__ float frcp(float x)  { return __builtin_amdgcn_rcpf(x); }

// fp32->bf16 split: hi = RNE(x); lo = trunc_bf16(x - hi).
__device__ __forceinline__ void bf_split(float x, short& hi, short& lo) {
  unsigned u = __builtin_bit_cast(unsigned, x);
  unsigned r = u + 0x7fffu + ((u >> 16) & 1u);
  hi = (short)(r >> 16);
  float hf = __builtin_bit_cast(float, r & 0xffff0000u);
  lo = (short)(__builtin_bit_cast(unsigned, x - hf) >> 16);
}

// ---------------- split-bf16 MFMA GEMM ---------------------------------------
// acc[m][n] = sum_k A[m][k]*W[n][k] + bias[n]; OUTPUT = exp2(C*acc)  (R11).
// x = hi + lo (both bf16); D = Ahi*Whi + Ahi*Wlo + Alo*Whi (lo*lo dropped).
// 64x64 tile, KC=64. by<16 -> query rows (Eq), else values rows (Ev).
// LDS rows padded to 72 shorts (144B). Grid (8,80).
__global__ __launch_bounds__(256) void proj_gemm_mfma(
    const float* __restrict__ query, const float* __restrict__ values,
    const float* __restrict__ Wq, const float* __restrict__ Wv,
    const float* __restrict__ bq, const float* __restrict__ bv,
    float* __restrict__ qp, float* __restrict__ vp)
{
  __shared__ short sAhi[64 * 72];
  __shared__ short sAlo[64 * 72];
  __shared__ short sWhi[64 * 72];
  __shared__ short sWlo[64 * 72];

  const int t    = threadIdx.x;
  const int lane = t & 63;
  const int w    = t >> 6;                  // wave 0..3
  const int by   = blockIdx.y;
  const bool isQ = (by < 16);
  const float* A    = isQ ? query : values;
  const float* W    = isQ ? Wq : Wv;
  const float* bias = isQ ? bq : bv;
  float*       out  = isQ ? qp : vp;
  const int m0 = (isQ ? by : (by - 16)) << 6;
  const int n0 = blockIdx.x << 6;

  // staging map: thread t, iter p: row = t>>2 (64 rows), f4-col = p*4 + (t&3)
  const int srow = t >> 2, scol = t & 3;
  const float* Ap = A + (size_t)(m0 + srow) * 512 + (scol << 2);
  const float* Wp = W + (size_t)(n0 + srow) * 512 + (scol << 2);

  const int mw = (w & 1) << 5, nw = (w >> 1) << 5;   // wave's 32x32 quadrant
  const int frow = lane & 15, fquad = lane >> 4;

  f32x4 acc[2][2] = {};
  float4 pfA[4], pfW[4];
#pragma unroll
  for (int p = 0; p < 4; ++p) {
    pfA[p] = *(const float4*)(Ap + (p << 4));
    pfW[p] = *(const float4*)(Wp + (p << 4));
  }

  for (int kc = 0; kc < 512; kc += 64) {
    __syncthreads();
#pragma unroll
    for (int p = 0; p < 4; ++p) {
      float av[4] = {pfA[p].x, pfA[p].y, pfA[p].z, pfA[p].w};
      float wv[4] = {pfW[p].x, pfW[p].y, pfW[p].z, pfW[p].w};
      short4 ah, al, wh, wl;
      short* ahp = (short*)&ah; short* alp = (short*)&al;
      short* whp = (short*)&wh; short* wlp = (short*)&wl;
#pragma unroll
      for (int k = 0; k < 4; ++k) {
        bf_split(av[k], ahp[k], alp[k]);
        bf_split(wv[k], whp[k], wlp[k]);
      }
      const int ofs = srow * 72 + ((p << 2) + scol) * 4;
      *(short4*)&sAhi[ofs] = ah; *(short4*)&sAlo[ofs] = al;
      *(short4*)&sWhi[ofs] = wh; *(short4*)&sWlo[ofs] = wl;
    }
    __syncthreads();
    if (kc + 64 < 512) {
#pragma unroll
      for (int p = 0; p < 4; ++p) {
        pfA[p] = *(const float4*)(Ap + kc + 64 + (p << 4));
        pfW[p] = *(const float4*)(Wp + kc + 64 + (p << 4));
      }
    }
#pragma unroll
    for (int kb = 0; kb < 2; ++kb) {
      const int ko = kb * 32 + fquad * 8;
      short8 ahi[2], alo[2], whi[2], wlo[2];
#pragma unroll
      for (int mt = 0; mt < 2; ++mt) {
        const int r = (mw + mt * 16 + frow) * 72 + ko;
        ahi[mt] = *(const short8*)&sAhi[r];
        alo[mt] = *(const short8*)&sAlo[r];
      }
#pragma unroll
      for (int nt = 0; nt < 2; ++nt) {
        const int r = (nw + nt * 16 + frow) * 72 + ko;
        whi[nt] = *(const short8*)&sWhi[r];
        wlo[nt] = *(const short8*)&sWlo[r];
      }
#pragma unroll
      for (int mt = 0; mt < 2; ++mt)
#pragma unroll
        for (int nt = 0; nt < 2; ++nt) {
          acc[mt][nt] = __builtin_amdgcn_mfma_f32_16x16x32_bf16(
              alo[mt], whi[nt], acc[mt][nt], 0, 0, 0);
          acc[mt][nt] = __builtin_amdgcn_mfma_f32_16x16x32_bf16(
              ahi[mt], wlo[nt], acc[mt][nt], 0, 0, 0);
          acc[mt][nt] = __builtin_amdgcn_mfma_f32_16x16x32_bf16(
              ahi[mt], whi[nt], acc[mt][nt], 0, 0, 0);
        }
    }
  }

  // epilogue: C/D layout col = lane&15, row = (lane>>4)*4 + reg.
  // R11: store exp2(C*(acc+bias)) -- Eq/Ev consumed multiplicatively by score.
#pragma unroll
  for (int nt = 0; nt < 2; ++nt) {
    const int n = n0 + nw + nt * 16 + frow;
    const float bn = bias[n];
#pragma unroll
    for (int mt = 0; mt < 2; ++mt) {
      float vreg[4] = {acc[mt][nt].x, acc[mt][nt].y, acc[mt][nt].z, acc[mt][nt].w};
#pragma unroll
      for (int r = 0; r < 4; ++r) {
        const int m = m0 + mw + mt * 16 + fquad * 4 + r;
        out[(size_t)m * 512 + n] = fexp2(C_SCALE * (vreg[r] + bn));
      }
    }
  }
}

// ---------------- score chunk (NU slot-steps, 16 slots apart) ----------------
// Eq-state (Eq0/Eq1/wc for all 8 j) hoisted by caller into registers; j-body:
// NU Ev loads + NU*4 pair-computes (1 trans + 9 VALU each). Static indexing.
template<int NU>
__device__ __forceinline__ void score_chunkB(
    const float* __restrict__ vpb,
    const float (&Eq0a)[8][4], const float (&Eq1a)[8][4], const float (&wca)[8][4],
    const int* idxs, float* __restrict__ ow0,
    int s00, int i0, int hi, int c4, int lane)
{
  int su[NU];
  unsigned voff[NU];
  float a0[NU], a1[NU];
#pragma unroll
  for (int u = 0; u < NU; ++u) {
    su[u] = s00 + ((i0 + u) << 4);
    voff[u] = ((unsigned)idxs[su[u] & 511] << 9) + (unsigned)c4;
    a0[u] = 0.f; a1[u] = 0.f;
  }
#pragma unroll
  for (int j = 0; j < 8; ++j) {
    float4 vv[NU];
#pragma unroll
    for (int u = 0; u < NU; ++u)
      vv[u] = *(const float4*)(vpb + voff[u] + (unsigned)(j << 6));
#pragma unroll
    for (int u = 0; u < NU; ++u) {
      const float Ev[4] = {vv[u].x, vv[u].y, vv[u].z, vv[u].w};
#pragma unroll
      for (int k = 0; k < 4; ++k) {
        float e0 = Ev[k] * Eq0a[j][k];
        float e1 = Ev[k] * Eq1a[j][k];
        float d0 = e0 + 1.0f;
        float d1 = e1 + 1.0f;
        float P  = frcp(d0 * d1);          // pair-rcp: r0=d1*P, r1=d0*P
        a0[u] = __builtin_fmaf(wca[j][k] * d1, P, a0[u]);
        a1[u] = __builtin_fmaf(wca[j][k] * d0, P, a1[u]);
      }
    }
  }
#pragma unroll
  for (int u = 0; u < NU; ++u) {
    float s0 = a0[u], s1 = a1[u];
#pragma unroll
    for (int off = 1; off < 16; off <<= 1) {
      s0 += __shfl_xor(s0, off, 64);
      s1 += __shfl_xor(s1, off, 64);
    }
    if (su[u] < hi && (lane & 15) == (i0 + u)) {   // i0+u <= 7 < 16
      ow0[su[u]]       = s0;
      ow0[512 + su[u]] = s1;
    }
  }
}

// ---------------- attn kernel A: raw scores ----------------------------------
// Grid (512 qpairs, 4 slot-chunks) x 256 thr (4 waves).
// PLAIN launch_bounds (no min-occupancy arg -- see HARD RULE above).
// Block covers slots [cnt*c/4, cnt*(c+1)/4); wave w, iter i owns slots
// lo + i*16 + w*4 + g (g = lane>>4); 16 h-lanes per slot (c4 = (lane&15)*4).
// Raw scores written slot-ordered into out_w rows (staging; finish rewrites).
__global__ __launch_bounds__(256) void attn_score(
    const float* __restrict__ qp, const float* __restrict__ vp,
    const int* __restrict__ mask, const float* __restrict__ wc,
    float* __restrict__ out_w)
{
  __shared__ int idxs[512];
  __shared__ int cnt8[8];

  const int t    = threadIdx.x;
  const int lane = t & 63;
  const int w    = t >> 6;                 // 0..3
  const int b    = blockIdx.x & 7;
  const int qg   = blockIdx.x >> 3;
  const int rowbase = b * 128 + qg * 2;

  idxs[t] = 0; idxs[t + 256] = 0;
  const int mv0 = mask[b * 512 + t];
  const int mv1 = mask[b * 512 + 256 + t];
  const unsigned long long bal0 = __ballot(mv0 != 0);
  const unsigned long long bal1 = __ballot(mv1 != 0);
  if (lane == 0) { cnt8[w] = __popcll(bal0); cnt8[w + 4] = __popcll(bal1); }
  __syncthreads();
  int cnt = 0, off0 = 0, off4 = 0;
#pragma unroll
  for (int j = 0; j < 8; ++j) {
    if (j == w)     off0 = cnt;
    if (j == w + 4) off4 = cnt;
    cnt += cnt8[j];
  }
  if (mv0) idxs[off0 + __popcll(bal0 & ((1ull << lane) - 1ull))] = t;
  if (mv1) idxs[off4 + __popcll(bal1 & ((1ull << lane) - 1ull))] = t + 256;
  __syncthreads();

  const int c  = blockIdx.y;               // slot-chunk 0..3
  const int lo = (cnt * c) >> 2;
  const int hi = (cnt * (c + 1)) >> 2;
  const int NI = (hi - lo + 15) >> 4;      // 16-slot steps (<=8)
  const int g  = lane >> 4;
  const int c4 = (lane & 15) << 2;
  const int s00 = lo + (w << 2) + g;

  const float* vpb = vp + (size_t)b * 512 * 512;
  const float* qr0 = qp + (size_t)rowbase * 512;
  float* ow0 = out_w + (size_t)rowbase * 512;

  // ---- hoist per-block Eq-state for all 8 j's (96 regs, static indices)
  float Eq0a[8][4], Eq1a[8][4], wca[8][4];
#pragma unroll
  for (int j = 0; j < 8; ++j) {
    const int hoff = (j << 6) + c4;
    const float4 q0v = *(const float4*)(qr0 + hoff);
    const float4 q1v = *(const float4*)(qr0 + 512 + hoff);
    const float4 wcv = *(const float4*)(wc + hoff);
    Eq0a[j][0] = q0v.x; Eq0a[j][1] = q0v.y; Eq0a[j][2] = q0v.z; Eq0a[j][3] = q0v.w;
    Eq1a[j][0] = q1v.x; Eq1a[j][1] = q1v.y; Eq1a[j][2] = q1v.z; Eq1a[j][3] = q1v.w;
    wca[j][0] = wcv.x; wca[j][1] = wcv.y; wca[j][2] = wcv.z; wca[j][3] = wcv.w;
  }

  int i0 = 0;
  for (; i0 + 4 <= NI; i0 += 4)
    score_chunkB<4>(vpb, Eq0a, Eq1a, wca, idxs, ow0, s00, i0, hi, c4, lane);
  for (; i0 < NI; ++i0)
    score_chunkB<1>(vpb, Eq0a, Eq1a, wca, idxs, ow0, s00, i0, hi, c4, lane);
}

// ---------------- attn kernel B: softmax + weights + context -----------------
// 512 blocks x 512 thr (8 waves). Reads slot-ordered raw scores from out_w,
// softmax (min-shift, invalid slots masked to +BIG), rewrites out_w rows
// coalesced via inverse map, context with wave-per-h-window.
__global__ __launch_bounds__(512) void attn_finish(
    const float* __restrict__ values, const int* __restrict__ mask,
    float* __restrict__ out_ctx, float* __restrict__ out_w)
{
  __shared__ int   idxs[512];
  __shared__ float wls2[512][2];    // final weights per slot, (q0,q1) pairs
  __shared__ int   cnt8[8];

  const int t    = threadIdx.x;
  const int lane = t & 63;
  const int w    = t >> 6;                 // 0..7
  const int b    = blockIdx.x & 7;
  const int qg   = blockIdx.x >> 3;
  const int rowbase = b * 128 + qg * 2;

  ((float*)wls2)[t]       = 0.f;
  ((float*)wls2)[t + 512] = 0.f;
  idxs[t] = 0;
  const int mv = mask[b * 512 + t];
  const unsigned long long bal = __ballot(mv != 0);
  if (lane == 0) cnt8[w] = __popcll(bal);
  __syncthreads();
  int cnt = 0, offw = 0;
#pragma unroll
  for (int j = 0; j < 8; ++j) { if (j == w) offw = cnt; cnt += cnt8[j]; }
  int iinv = -1;
  if (mv) {
    iinv = offw + __popcll(bal & ((1ull << lane) - 1ull));
    idxs[iinv] = t;
  }
  __syncthreads();

  // ---- softmax: waves 0-3 -> q0, 4-7 -> q1 (dup compute; waves 0/4 write)
  {
    const int mq = (w >= 4) ? 1 : 0;
    const float* srow = out_w + (size_t)(rowbase + mq) * 512;
    float4 u0 = ((const float4*)srow)[lane * 2];
    float4 u1 = ((const float4*)srow)[lane * 2 + 1];
    float s8[8] = {u0.x, u0.y, u0.z, u0.w, u1.x, u1.y, u1.z, u1.w};
#pragma unroll
    for (int k = 0; k < 8; ++k)
      if (lane * 8 + k >= cnt) s8[k] = 3.4e38f;           // mask garbage slots
    float m = s8[0];
#pragma unroll
    for (int k = 1; k < 8; ++k) m = fminf(m, s8[k]);      // min: weight=exp2(C*(m-s))
#pragma unroll
    for (int off = 1; off < 64; off <<= 1) m = fminf(m, __shfl_xor(m, off, 64));
    float e[8], S = 0.f;
#pragma unroll
    for (int k = 0; k < 8; ++k) { e[k] = fexp2(C_SCALE * (m - s8[k])); S += e[k]; }
#pragma unroll
    for (int off = 1; off < 64; off <<= 1) S += __shfl_xor(S, off, 64);
    const float rinv = frcp(S);
    if (w == 0 || w == 4) {
#pragma unroll
      for (int k = 0; k < 8; ++k) {
        const int s = lane * 8 + k;
        if (s < cnt) wls2[s][mq] = e[k] * rinv;
      }
    }
  }
  __syncthreads();

  // ---- final weight rows (coalesced; zeros where masked out)
  {
    float w0 = 0.f, w1 = 0.f;
    if (iinv >= 0) { w0 = wls2[iinv][0]; w1 = wls2[iinv][1]; }
    out_w[(size_t)rowbase * 512 + t]       = w0;
    out_w[(size_t)(rowbase + 1) * 512 + t] = w1;
  }

  // ---- context: wave w owns h-window [w*64, w*64+64)
  const int NC = (cnt + 3) >> 2;
  const int g  = lane >> 4;
  const int c4 = (lane & 15) << 2;
  const unsigned hbase = (unsigned)(w * 64 + c4);
  const float* vb = values + (size_t)b * 512 * 512;
  float c0[4] = {0.f, 0.f, 0.f, 0.f}, c1[4] = {0.f, 0.f, 0.f, 0.f};
#pragma unroll 4
  for (int i = 0; i < NC; ++i) {
    const int s = (i << 2) + g;
    const unsigned ro = ((unsigned)idxs[s] << 9) + hbase;
    const float2 wg = *(const float2*)&wls2[s][0];        // padded slots: 0
    const float4 v4 = *(const float4*)(vb + ro);
    float vv[4] = {v4.x, v4.y, v4.z, v4.w};
#pragma unroll
    for (int k = 0; k < 4; ++k) {
      c0[k] = __builtin_fmaf(wg.x, vv[k], c0[k]);
      c1[k] = __builtin_fmaf(wg.y, vv[k], c1[k]);
    }
  }
#pragma unroll
  for (int k = 0; k < 4; ++k) {                           // reduce over g
    c0[k] += __shfl_xor(c0[k], 16, 64); c0[k] += __shfl_xor(c0[k], 32, 64);
    c1[k] += __shfl_xor(c1[k], 16, 64); c1[k] += __shfl_xor(c1[k], 32, 64);
  }
  if (lane < 16) {
    float4 o0 = {c0[0], c0[1], c0[2], c0[3]};
    float4 o1 = {c1[0], c1[1], c1[2], c1[3]};
    *(float4*)(out_ctx + (size_t)rowbase * 512 + w * 64 + lane * 4)       = o0;
    *(float4*)(out_ctx + (size_t)(rowbase + 1) * 512 + w * 64 + lane * 4) = o1;
  }
}

extern "C" void kernel_launch(void* const* d_in, const int* in_sizes, int n_in,
                              void* d_out, int out_size, void* d_ws, size_t ws_size,
                              hipStream_t stream) {
  const float* query  = (const float*)d_in[0];
  const float* values = (const float*)d_in[1];
  const int*   mask   = (const int*)d_in[2];
  const float* Wq     = (const float*)d_in[3];
  const float* bq     = (const float*)d_in[4];
  const float* Wv     = (const float*)d_in[5];
  const float* bv     = (const float*)d_in[6];
  const float* wc     = (const float*)d_in[7];
  // d_in[8] = bc: no effect on outputs (softmax shift-invariance) -> dropped.

  float* out   = (float*)d_out;
  float* out_w = out + (size_t)8 * 128 * 512;
  float* qp    = (float*)d_ws;                 // Eq: 1024 x 512
  float* vp    = qp + (size_t)1024 * 512;      // Ev: 4096 x 512

  proj_gemm_mfma<<<dim3(8, 80), 256, 0, stream>>>(query, values, Wq, Wv, bq, bv, qp, vp);
  attn_score<<<dim3(512, 4), 256, 0, stream>>>(qp, vp, mask, wc, out_w);
  attn_finish<<<512, 512, 0, stream>>>(values, mask, out, out_w);
}

// Round 11
// 137.126 us; speedup vs baseline: 1.0766x; 1.0260x over previous
//
#include <hip/hip_runtime.h>
#include <hip/hip_bf16.h>

// AdditiveAttention: B=8, Q=128, V=512, H=512.
// out = [context (B*Q*H) | weights (B*Q*V)] fp32.
// ws: Eq [1024*512] f32 @0, Ev [4096*512] f32 @2MB (10MB total).
// bc dropped (softmax shift-invariant); sum_h wc[h] const also cancels.
// Score math: tanh(y)=1-2r, r=1/(2^(C*y)+1), C=2*log2(e);
//   softmax arg = -C * sum_h wc[h]*r  (consts dropped).
// HARD RULE (R0..R5): NO min-occupancy arg in launch_bounds, ever.
// HARD RULE (R12): NO hand-written VOP3P packed-f32 inline asm -- R12's
//   v_pk_* asm silently computed garbage (absmax 4.36; op_sel_hi/alignment
//   hazards). Packed f32 only via <2 x float> vector source, backend-lowered.
// R11: factorized exp (Ev=exp2(C*vp), Eq=exp2(C*qp) stored by proj) -- WIN.
// R13: R12's packed layout retained, inner loop as native f32x2 arithmetic
//   (+ __builtin_elementwise_fma). Bit-identical per-element IEEE ops.

#define C_SCALE 2.8853900817779268f

typedef __attribute__((ext_vector_type(8))) short short8;
typedef __attribute__((ext_vector_type(4))) float f32x4;
typedef __attribute__((ext_vector_type(2))) float f32x2;

__device__ __forceinline__ float fexp2(float x) { return __builtin_amdgcn_exp2f(x); }
__device__ __forceinline__ float frcp(float x)  { return __builtin_amdgcn_rcpf(x); }

// fp32->bf16 split: hi = RNE(x); lo = trunc_bf16(x - hi).
__device__ __forceinline__ void bf_split(float x, short& hi, short& lo) {
  unsigned u = __builtin_bit_cast(unsigned, x);
  unsigned r = u + 0x7fffu + ((u >> 16) & 1u);
  hi = (short)(r >> 16);
  float hf = __builtin_bit_cast(float, r & 0xffff0000u);
  lo = (short)(__builtin_bit_cast(unsigned, x - hf) >> 16);
}

// ---------------- split-bf16 MFMA GEMM ---------------------------------------
// acc[m][n] = sum_k A[m][k]*W[n][k] + bias[n]; OUTPUT = exp2(C*acc)  (R11).
// x = hi + lo (both bf16); D = Ahi*Whi + Ahi*Wlo + Alo*Whi (lo*lo dropped).
// 64x64 tile, KC=64. by<16 -> query rows (Eq), else values rows (Ev).
// LDS rows padded to 72 shorts (144B). Grid (8,80).
__global__ __launch_bounds__(256) void proj_gemm_mfma(
    const float* __restrict__ query, const float* __restrict__ values,
    const float* __restrict__ Wq, const float* __restrict__ Wv,
    const float* __restrict__ bq, const float* __restrict__ bv,
    float* __restrict__ qp, float* __restrict__ vp)
{
  __shared__ short sAhi[64 * 72];
  __shared__ short sAlo[64 * 72];
  __shared__ short sWhi[64 * 72];
  __shared__ short sWlo[64 * 72];

  const int t    = threadIdx.x;
  const int lane = t & 63;
  const int w    = t >> 6;                  // wave 0..3
  const int by   = blockIdx.y;
  const bool isQ = (by < 16);
  const float* A    = isQ ? query : values;
  const float* W    = isQ ? Wq : Wv;
  const float* bias = isQ ? bq : bv;
  float*       out  = isQ ? qp : vp;
  const int m0 = (isQ ? by : (by - 16)) << 6;
  const int n0 = blockIdx.x << 6;

  // staging map: thread t, iter p: row = t>>2 (64 rows), f4-col = p*4 + (t&3)
  const int srow = t >> 2, scol = t & 3;
  const float* Ap = A + (size_t)(m0 + srow) * 512 + (scol << 2);
  const float* Wp = W + (size_t)(n0 + srow) * 512 + (scol << 2);

  const int mw = (w & 1) << 5, nw = (w >> 1) << 5;   // wave's 32x32 quadrant
  const int frow = lane & 15, fquad = lane >> 4;

  f32x4 acc[2][2] = {};
  float4 pfA[4], pfW[4];
#pragma unroll
  for (int p = 0; p < 4; ++p) {
    pfA[p] = *(const float4*)(Ap + (p << 4));
    pfW[p] = *(const float4*)(Wp + (p << 4));
  }

  for (int kc = 0; kc < 512; kc += 64) {
    __syncthreads();
#pragma unroll
    for (int p = 0; p < 4; ++p) {
      float av[4] = {pfA[p].x, pfA[p].y, pfA[p].z, pfA[p].w};
      float wv[4] = {pfW[p].x, pfW[p].y, pfW[p].z, pfW[p].w};
      short4 ah, al, wh, wl;
      short* ahp = (short*)&ah; short* alp = (short*)&al;
      short* whp = (short*)&wh; short* wlp = (short*)&wl;
#pragma unroll
      for (int k = 0; k < 4; ++k) {
        bf_split(av[k], ahp[k], alp[k]);
        bf_split(wv[k], whp[k], wlp[k]);
      }
      const int ofs = srow * 72 + ((p << 2) + scol) * 4;
      *(short4*)&sAhi[ofs] = ah; *(short4*)&sAlo[ofs] = al;
      *(short4*)&sWhi[ofs] = wh; *(short4*)&sWlo[ofs] = wl;
    }
    __syncthreads();
    if (kc + 64 < 512) {
#pragma unroll
      for (int p = 0; p < 4; ++p) {
        pfA[p] = *(const float4*)(Ap + kc + 64 + (p << 4));
        pfW[p] = *(const float4*)(Wp + kc + 64 + (p << 4));
      }
    }
#pragma unroll
    for (int kb = 0; kb < 2; ++kb) {
      const int ko = kb * 32 + fquad * 8;
      short8 ahi[2], alo[2], whi[2], wlo[2];
#pragma unroll
      for (int mt = 0; mt < 2; ++mt) {
        const int r = (mw + mt * 16 + frow) * 72 + ko;
        ahi[mt] = *(const short8*)&sAhi[r];
        alo[mt] = *(const short8*)&sAlo[r];
      }
#pragma unroll
      for (int nt = 0; nt < 2; ++nt) {
        const int r = (nw + nt * 16 + frow) * 72 + ko;
        whi[nt] = *(const short8*)&sWhi[r];
        wlo[nt] = *(const short8*)&sWlo[r];
      }
#pragma unroll
      for (int mt = 0; mt < 2; ++mt)
#pragma unroll
        for (int nt = 0; nt < 2; ++nt) {
          acc[mt][nt] = __builtin_amdgcn_mfma_f32_16x16x32_bf16(
              alo[mt], whi[nt], acc[mt][nt], 0, 0, 0);
          acc[mt][nt] = __builtin_amdgcn_mfma_f32_16x16x32_bf16(
              ahi[mt], wlo[nt], acc[mt][nt], 0, 0, 0);
          acc[mt][nt] = __builtin_amdgcn_mfma_f32_16x16x32_bf16(
              ahi[mt], whi[nt], acc[mt][nt], 0, 0, 0);
        }
    }
  }

  // epilogue: C/D layout col = lane&15, row = (lane>>4)*4 + reg.
  // R11: store exp2(C*(acc+bias)) -- Eq/Ev consumed multiplicatively by score.
#pragma unroll
  for (int nt = 0; nt < 2; ++nt) {
    const int n = n0 + nw + nt * 16 + frow;
    const float bn = bias[n];
#pragma unroll
    for (int mt = 0; mt < 2; ++mt) {
      float vreg[4] = {acc[mt][nt].x, acc[mt][nt].y, acc[mt][nt].z, acc[mt][nt].w};
#pragma unroll
      for (int r = 0; r < 4; ++r) {
        const int m = m0 + mw + mt * 16 + fquad * 4 + r;
        out[(size_t)m * 512 + n] = fexp2(C_SCALE * (vreg[r] + bn));
      }
    }
  }
}

// ---------------- score chunk (NU slot-steps, 16 slots apart) ----------------
// Inner loop in f32x2 vector arithmetic (backend may lower to v_pk_*_f32;
// NO inline asm -- see HARD RULE R12). Per-element math identical to R11.
template<int NU>
__device__ __forceinline__ void score_chunkC(
    const float* __restrict__ vpb,
    const f32x2 (&Eq0a)[8][2], const f32x2 (&Eq1a)[8][2], const f32x2 (&wca)[8][2],
    const int* idxs, float* __restrict__ ow0,
    int s00, int i0, int hi, int c4, int lane)
{
  int su[NU];
  unsigned voff[NU];
  f32x2 a0[NU], a1[NU];
#pragma unroll
  for (int u = 0; u < NU; ++u) {
    su[u] = s00 + ((i0 + u) << 4);
    voff[u] = ((unsigned)idxs[su[u] & 511] << 9) + (unsigned)c4;
    a0[u] = (f32x2){0.f, 0.f}; a1[u] = (f32x2){0.f, 0.f};
  }
  const f32x2 one2 = {1.f, 1.f};
#pragma unroll
  for (int j = 0; j < 8; ++j) {
    float4 vv[NU];
#pragma unroll
    for (int u = 0; u < NU; ++u)
      vv[u] = *(const float4*)(vpb + voff[u] + (unsigned)(j << 6));
#pragma unroll
    for (int u = 0; u < NU; ++u) {
      const f32x2 Ev[2] = {{vv[u].x, vv[u].y}, {vv[u].z, vv[u].w}};
#pragma unroll
      for (int kp = 0; kp < 2; ++kp) {
        f32x2 e0 = Ev[kp] * Eq0a[j][kp];
        f32x2 e1 = Ev[kp] * Eq1a[j][kp];
        f32x2 d0 = e0 + one2;
        f32x2 d1 = e1 + one2;
        f32x2 pr = d0 * d1;
        f32x2 P  = {frcp(pr.x), frcp(pr.y)};       // pair-rcp per q-pair
        a0[u] = __builtin_elementwise_fma(wca[j][kp] * d1, P, a0[u]);
        a1[u] = __builtin_elementwise_fma(wca[j][kp] * d0, P, a1[u]);
      }
    }
  }
#pragma unroll
  for (int u = 0; u < NU; ++u) {
    float s0 = a0[u].x + a0[u].y;
    float s1 = a1[u].x + a1[u].y;
#pragma unroll
    for (int off = 1; off < 16; off <<= 1) {
      s0 += __shfl_xor(s0, off, 64);
      s1 += __shfl_xor(s1, off, 64);
    }
    if (su[u] < hi && (lane & 15) == (i0 + u)) {   // i0+u <= 7 < 16
      ow0[su[u]]       = s0;
      ow0[512 + su[u]] = s1;
    }
  }
}

// ---------------- attn kernel A: raw scores ----------------------------------
// Grid (512 qpairs, 4 slot-chunks) x 256 thr (4 waves).
// PLAIN launch_bounds (no min-occupancy arg -- see HARD RULE above).
// Block covers slots [cnt*c/4, cnt*(c+1)/4); wave w, iter i owns slots
// lo + i*16 + w*4 + g (g = lane>>4); 16 h-lanes per slot (c4 = (lane&15)*4).
// Raw scores written slot-ordered into out_w rows (staging; finish rewrites).
__global__ __launch_bounds__(256) void attn_score(
    const float* __restrict__ qp, const float* __restrict__ vp,
    const int* __restrict__ mask, const float* __restrict__ wc,
    float* __restrict__ out_w)
{
  __shared__ int idxs[512];
  __shared__ int cnt8[8];

  const int t    = threadIdx.x;
  const int lane = t & 63;
  const int w    = t >> 6;                 // 0..3
  const int b    = blockIdx.x & 7;
  const int qg   = blockIdx.x >> 3;
  const int rowbase = b * 128 + qg * 2;

  idxs[t] = 0; idxs[t + 256] = 0;
  const int mv0 = mask[b * 512 + t];
  const int mv1 = mask[b * 512 + 256 + t];
  const unsigned long long bal0 = __ballot(mv0 != 0);
  const unsigned long long bal1 = __ballot(mv1 != 0);
  if (lane == 0) { cnt8[w] = __popcll(bal0); cnt8[w + 4] = __popcll(bal1); }
  __syncthreads();
  int cnt = 0, off0 = 0, off4 = 0;
#pragma unroll
  for (int j = 0; j < 8; ++j) {
    if (j == w)     off0 = cnt;
    if (j == w + 4) off4 = cnt;
    cnt += cnt8[j];
  }
  if (mv0) idxs[off0 + __popcll(bal0 & ((1ull << lane) - 1ull))] = t;
  if (mv1) idxs[off4 + __popcll(bal1 & ((1ull << lane) - 1ull))] = t + 256;
  __syncthreads();

  const int c  = blockIdx.y;               // slot-chunk 0..3
  const int lo = (cnt * c) >> 2;
  const int hi = (cnt * (c + 1)) >> 2;
  const int NI = (hi - lo + 15) >> 4;      // 16-slot steps (<=8)
  const int g  = lane >> 4;
  const int c4 = (lane & 15) << 2;
  const int s00 = lo + (w << 2) + g;

  const float* vpb = vp + (size_t)b * 512 * 512;
  const float* qr0 = qp + (size_t)rowbase * 512;
  float* ow0 = out_w + (size_t)rowbase * 512;

  // ---- hoist per-block Eq-state for all 8 j's (96 regs, static indices)
  f32x2 Eq0a[8][2], Eq1a[8][2], wca[8][2];
#pragma unroll
  for (int j = 0; j < 8; ++j) {
    const int hoff = (j << 6) + c4;
    const float4 q0v = *(const float4*)(qr0 + hoff);
    const float4 q1v = *(const float4*)(qr0 + 512 + hoff);
    const float4 wcv = *(const float4*)(wc + hoff);
    Eq0a[j][0] = (f32x2){q0v.x, q0v.y}; Eq0a[j][1] = (f32x2){q0v.z, q0v.w};
    Eq1a[j][0] = (f32x2){q1v.x, q1v.y}; Eq1a[j][1] = (f32x2){q1v.z, q1v.w};
    wca[j][0]  = (f32x2){wcv.x, wcv.y}; wca[j][1]  = (f32x2){wcv.z, wcv.w};
  }

  int i0 = 0;
  for (; i0 + 4 <= NI; i0 += 4)
    score_chunkC<4>(vpb, Eq0a, Eq1a, wca, idxs, ow0, s00, i0, hi, c4, lane);
  for (; i0 < NI; ++i0)
    score_chunkC<1>(vpb, Eq0a, Eq1a, wca, idxs, ow0, s00, i0, hi, c4, lane);
}

// ---------------- attn kernel B: softmax + weights + context -----------------
// 512 blocks x 512 thr (8 waves). Reads slot-ordered raw scores from out_w,
// softmax (min-shift, invalid slots masked to +BIG), rewrites out_w rows
// coalesced via inverse map, context with wave-per-h-window.
__global__ __launch_bounds__(512) void attn_finish(
    const float* __restrict__ values, const int* __restrict__ mask,
    float* __restrict__ out_ctx, float* __restrict__ out_w)
{
  __shared__ int   idxs[512];
  __shared__ float wls2[512][2];    // final weights per slot, (q0,q1) pairs
  __shared__ int   cnt8[8];

  const int t    = threadIdx.x;
  const int lane = t & 63;
  const int w    = t >> 6;                 // 0..7
  const int b    = blockIdx.x & 7;
  const int qg   = blockIdx.x >> 3;
  const int rowbase = b * 128 + qg * 2;

  ((float*)wls2)[t]       = 0.f;
  ((float*)wls2)[t + 512] = 0.f;
  idxs[t] = 0;
  const int mv = mask[b * 512 + t];
  const unsigned long long bal = __ballot(mv != 0);
  if (lane == 0) cnt8[w] = __popcll(bal);
  __syncthreads();
  int cnt = 0, offw = 0;
#pragma unroll
  for (int j = 0; j < 8; ++j) { if (j == w) offw = cnt; cnt += cnt8[j]; }
  int iinv = -1;
  if (mv) {
    iinv = offw + __popcll(bal & ((1ull << lane) - 1ull));
    idxs[iinv] = t;
  }
  __syncthreads();

  // ---- softmax: waves 0-3 -> q0, 4-7 -> q1 (dup compute; waves 0/4 write)
  {
    const int mq = (w >= 4) ? 1 : 0;
    const float* srow = out_w + (size_t)(rowbase + mq) * 512;
    float4 u0 = ((const float4*)srow)[lane * 2];
    float4 u1 = ((const float4*)srow)[lane * 2 + 1];
    float s8[8] = {u0.x, u0.y, u0.z, u0.w, u1.x, u1.y, u1.z, u1.w};
#pragma unroll
    for (int k = 0; k < 8; ++k)
      if (lane * 8 + k >= cnt) s8[k] = 3.4e38f;           // mask garbage slots
    float m = s8[0];
#pragma unroll
    for (int k = 1; k < 8; ++k) m = fminf(m, s8[k]);      // min: weight=exp2(C*(m-s))
#pragma unroll
    for (int off = 1; off < 64; off <<= 1) m = fminf(m, __shfl_xor(m, off, 64));
    float e[8], S = 0.f;
#pragma unroll
    for (int k = 0; k < 8; ++k) { e[k] = fexp2(C_SCALE * (m - s8[k])); S += e[k]; }
#pragma unroll
    for (int off = 1; off < 64; off <<= 1) S += __shfl_xor(S, off, 64);
    const float rinv = frcp(S);
    if (w == 0 || w == 4) {
#pragma unroll
      for (int k = 0; k < 8; ++k) {
        const int s = lane * 8 + k;
        if (s < cnt) wls2[s][mq] = e[k] * rinv;
      }
    }
  }
  __syncthreads();

  // ---- final weight rows (coalesced; zeros where masked out)
  {
    float w0 = 0.f, w1 = 0.f;
    if (iinv >= 0) { w0 = wls2[iinv][0]; w1 = wls2[iinv][1]; }
    out_w[(size_t)rowbase * 512 + t]       = w0;
    out_w[(size_t)(rowbase + 1) * 512 + t] = w1;
  }

  // ---- context: wave w owns h-window [w*64, w*64+64)
  const int NC = (cnt + 3) >> 2;
  const int g  = lane >> 4;
  const int c4 = (lane & 15) << 2;
  const unsigned hbase = (unsigned)(w * 64 + c4);
  const float* vb = values + (size_t)b * 512 * 512;
  float c0[4] = {0.f, 0.f, 0.f, 0.f}, c1[4] = {0.f, 0.f, 0.f, 0.f};
#pragma unroll 4
  for (int i = 0; i < NC; ++i) {
    const int s = (i << 2) + g;
    const unsigned ro = ((unsigned)idxs[s] << 9) + hbase;
    const float2 wg = *(const float2*)&wls2[s][0];        // padded slots: 0
    const float4 v4 = *(const float4*)(vb + ro);
    float vv[4] = {v4.x, v4.y, v4.z, v4.w};
#pragma unroll
    for (int k = 0; k < 4; ++k) {
      c0[k] = __builtin_fmaf(wg.x, vv[k], c0[k]);
      c1[k] = __builtin_fmaf(wg.y, vv[k], c1[k]);
    }
  }
#pragma unroll
  for (int k = 0; k < 4; ++k) {                           // reduce over g
    c0[k] += __shfl_xor(c0[k], 16, 64); c0[k] += __shfl_xor(c0[k], 32, 64);
    c1[k] += __shfl_xor(c1[k], 16, 64); c1[k] += __shfl_xor(c1[k], 32, 64);
  }
  if (lane < 16) {
    float4 o0 = {c0[0], c0[1], c0[2], c0[3]};
    float4 o1 = {c1[0], c1[1], c1[2], c1[3]};
    *(float4*)(out_ctx + (size_t)rowbase * 512 + w * 64 + lane * 4)       = o0;
    *(float4*)(out_ctx + (size_t)(rowbase + 1) * 512 + w * 64 + lane * 4) = o1;
  }
}

extern "C" void kernel_launch(void* const* d_in, const int* in_sizes, int n_in,
                              void* d_out, int out_size, void* d_ws, size_t ws_size,
                              hipStream_t stream) {
  const float* query  = (const float*)d_in[0];
  const float* values = (const float*)d_in[1];
  const int*   mask   = (const int*)d_in[2];
  const float* Wq     = (const float*)d_in[3];
  const float* bq     = (const float*)d_in[4];
  const float* Wv     = (const float*)d_in[5];
  const float* bv     = (const float*)d_in[6];
  const float* wc     = (const float*)d_in[7];
  // d_in[8] = bc: no effect on outputs (softmax shift-invariance) -> dropped.

  float* out   = (float*)d_out;
  float* out_w = out + (size_t)8 * 128 * 512;
  float* qp    = (float*)d_ws;                 // Eq: 1024 x 512
  float* vp    = qp + (size_t)1024 * 512;      // Ev: 4096 x 512

  proj_gemm_mfma<<<dim3(8, 80), 256, 0, stream>>>(query, values, Wq, Wv, bq, bv, qp, vp);
  attn_score<<<dim3(512, 4), 256, 0, stream>>>(qp, vp, mask, wc, out_w);
  attn_finish<<<512, 512, 0, stream>>>(values, mask, out, out_w);
}